// Round 6
// baseline (114.795 us; speedup 1.0000x reference)
//
#include <hip/hip_runtime.h>
#include <math.h>

// LevelSelect: FCOS-style FPN level assignment.
//   cls_pred   float32 (B=8, TOTAL=13343, C=80)
//   regr_pred  float32 (B, TOTAL, 4)
//   feature_shapes int32 (unused, hardcoded)
//   gt_boxes   float32 (B, 100, 5)  x1,y1,x2,y2,label
// Output: int32 (B,100): selected level per box, -1 for invalid.
//
// SEMANTICS (rounds 0-5 post-mortem, all six observations consistent):
//  * The mask multiply is evaluated as select(mask, loss, 0): out-of-mask
//    NaN/inf cells are DROPPED (full-grid poison ruled out by R2/R3/R4).
//  * NaN arises only from MASKED cells whose center lies outside the box
//    (possible only at strides 64/128 since boxes are >=32px): per-box NaN
//    set is a subset of {3,4}.
//  * Argmin NaN rule: FIRST NaN wins and is STICKY (numpy semantics, ref=np):
//    R5's last-NaN rule scored absmax exactly 1.0 -- the {3,4}-double-NaN
//    boxes (widths 32-64px) are the only disagreement, off by exactly 1.
// Implemented: masked-only sums (f64 accumulate; NaN/inf propagate; strict
// non-contracted f32 per-cell math in reference op order), then sticky
// first-NaN argmin, -1 for invalid boxes.

#define NCLS   80
#define NLEV   5
#define MAXGT  100
#define TOTAL  13343
#define BLK    64

__device__ __forceinline__ float fadd(float a, float b) { return __fadd_rn(a, b); }
__device__ __forceinline__ float fsub(float a, float b) { return __fsub_rn(a, b); }
__device__ __forceinline__ float fmul(float a, float b) { return __fmul_rn(a, b); }
__device__ __forceinline__ float fdv (float a, float b) { return __fdiv_rn(a, b); }

__device__ __forceinline__ double waveSumD(double v) {
    #pragma unroll
    for (int o = 32; o > 0; o >>= 1) v += __shfl_down(v, o, 64);
    return v;   // lane 0 holds the wave total
}

__global__ __launch_bounds__(BLK) void level_select_kernel(
    const float* __restrict__ cls_pred,
    const float* __restrict__ regr_pred,
    const float* __restrict__ gt_boxes,
    int* __restrict__ out)
{
    constexpr int fdim[NLEV]    = {100, 50, 25, 13, 7};
    constexpr int strides[NLEV] = {8, 16, 32, 64, 128};
    constexpr int starts[NLEV]  = {0, 10000, 12500, 13125, 13294};

    const int bn  = blockIdx.x;           // 0..799, one wave per (b, gt)
    const int b   = bn / MAXGT;
    const int tid = threadIdx.x;

    const float* box = gt_boxes + (size_t)bn * 5;
    const float b0 = box[0], b1 = box[1], b2 = box[2], b3 = box[3];
    const int   label = (int)box[4];

    const float* clsB = cls_pred  + (size_t)b * TOTAL * NCLS;
    const float* rgB  = regr_pred + (size_t)b * TOTAL * 4;

    double lv[NLEV];   // per-level loss (meaningful on lane 0)

    #pragma unroll
    for (int l = 0; l < NLEV; ++l) {
        const int   fw = fdim[l];
        const float st = (float)strides[l];

        // mask rectangle (strict f32, reference op order)
        const float pb0 = fdv(b0, st), pb1 = fdv(b1, st);
        const float pb2 = fdv(b2, st), pb3 = fdv(b3, st);
        const float cx = fdv(fadd(pb0, pb2), 2.0f);
        const float cy = fdv(fadd(pb1, pb3), 2.0f);
        const float hw = fdv(fmul(fsub(pb2, pb0), 0.2f), 2.0f);
        const float hh = fdv(fmul(fsub(pb3, pb1), 0.2f), 2.0f);
        const int x1 = (int)fminf(fmaxf(floorf(fsub(cx, hw)), 0.0f), (float)(fw - 1));
        const int y1 = (int)fminf(fmaxf(floorf(fsub(cy, hh)), 0.0f), (float)(fdim[l] - 1));
        const int x2 = min(max((int)ceilf(fadd(cx, hw)), x1 + 1), fw);
        const int y2 = min(max((int)ceilf(fadd(cy, hh)), y1 + 1), fdim[l]);
        const int w     = x2 - x1;
        const int cells = w * (y2 - y1);   // == cnt (rect always in-grid, >=1)

        double aiou = 0.0, acls = 0.0;

        for (int c = tid; c < cells; c += BLK) {
            const int x = x1 + c % w;
            const int y = y1 + c / w;
            const int p = starts[l] + y * fw + x;

            // ---- IoU term (strict f32; NaN/inf propagate into f64 sum) ----
            const float4 rp = *(const float4*)(rgB + (size_t)p * 4);
            const float sx = fmul(fadd((float)x, 0.5f), st);
            const float sy = fmul(fadd((float)y, 0.5f), st);
            const float tl = fdv(fsub(sx, b0), 4.0f);
            const float tt = fdv(fsub(sy, b1), 4.0f);
            const float tr = fdv(fsub(b2, sx), 4.0f);
            const float tb = fdv(fsub(b3, sy), 4.0f);
            const float t_area = fmul(fadd(tl, tr), fadd(tt, tb));
            const float p_area = fmul(fadd(rp.x, rp.z), fadd(rp.y, rp.w));
            const float wi = fadd(fminf(rp.x, tl), fminf(rp.z, tr));
            const float hi = fadd(fminf(rp.y, tt), fminf(rp.w, tb));
            const float ai = fmul(wi, hi);
            const float num = fadd(ai, 1.0f);
            const float den = fadd(fsub(fadd(t_area, p_area), ai), 1.0f);
            aiou += (double)(-logf(fdv(num, den)));   // NaN / +-inf faithful

            // ---- focal classification term ----
            const float4* row = (const float4*)(clsB + (size_t)p * NCLS);
            double sneg = 0.0;
            #pragma unroll
            for (int q = 0; q < NCLS / 4; ++q) {
                float4 v = row[q];
                {
                    const float cp = fminf(fmaxf(v.x, 1e-6f), 1.0f - 1e-6f);
                    sneg += (double)(0.75f * cp * cp * (-logf(1.0f - cp)));
                }
                {
                    const float cp = fminf(fmaxf(v.y, 1e-6f), 1.0f - 1e-6f);
                    sneg += (double)(0.75f * cp * cp * (-logf(1.0f - cp)));
                }
                {
                    const float cp = fminf(fmaxf(v.z, 1e-6f), 1.0f - 1e-6f);
                    sneg += (double)(0.75f * cp * cp * (-logf(1.0f - cp)));
                }
                {
                    const float cp = fminf(fmaxf(v.w, 1e-6f), 1.0f - 1e-6f);
                    sneg += (double)(0.75f * cp * cp * (-logf(1.0f - cp)));
                }
            }
            const float plab = fminf(fmaxf(clsB[(size_t)p * NCLS + label], 1e-6f), 1.0f - 1e-6f);
            const float neg_lab = 0.75f * plab * plab * (-logf(1.0f - plab));
            const float one_m = 1.0f - plab;
            const float pos_lab = 0.25f * one_m * one_m * (-logf(plab));
            acls += sneg - (double)neg_lab + (double)pos_lab;
        }

        aiou = waveSumD(aiou);
        acls = waveSumD(acls);
        lv[l] = aiou / (double)cells + acls / (double)cells;  // lane 0 valid
    }

    if (tid == 0) {
        // numpy argmin semantics: FIRST NaN is sticky; else strict-< argmin
        // (first index wins ties).
        double best   = INFINITY;
        int    idx    = 0;
        bool   accNan = false;
        #pragma unroll
        for (int l = 0; l < NLEV; ++l) {
            const double v = lv[l];
            if (!accNan && (isnan(v) || v < best)) {
                best = v; idx = l; accNan = isnan(v);
            }
        }
        const float vsum = fabsf(b0) + fabsf(b1) + fabsf(b2) + fabsf(b3);
        out[bn] = (vsum > 0.0f) ? idx : -1;
    }
}

extern "C" void kernel_launch(void* const* d_in, const int* in_sizes, int n_in,
                              void* d_out, int out_size, void* d_ws, size_t ws_size,
                              hipStream_t stream) {
    (void)d_ws; (void)ws_size; (void)out_size;
    const float* cls_pred  = (const float*)d_in[0];
    const float* regr_pred = (const float*)d_in[1];
    const float* gt_boxes  = (const float*)d_in[3];
    for (int i = 0; i < n_in; ++i) {   // defensive mapping by element count
        if      (in_sizes[i] == 8 * TOTAL * NCLS) cls_pred  = (const float*)d_in[i];
        else if (in_sizes[i] == 8 * TOTAL * 4)    regr_pred = (const float*)d_in[i];
        else if (in_sizes[i] == 8 * MAXGT * 5)    gt_boxes  = (const float*)d_in[i];
    }
    int* out = (int*)d_out;

    level_select_kernel<<<8 * MAXGT, BLK, 0, stream>>>(cls_pred, regr_pred, gt_boxes, out);
}

// Round 7
// 89.258 us; speedup vs baseline: 1.2861x; 1.2861x over previous
//
#include <hip/hip_runtime.h>
#include <math.h>

// LevelSelect: FCOS-style FPN level assignment.  (R6 passed: absmax 0)
// Semantics locked (rounds 0-6): masked-cells-only evaluation (XLA
// select-rewrite drops out-of-mask NaN/inf), strict non-contracted f32
// per-cell math in reference op order, f64 accumulation, numpy argmin with
// STICKY FIRST-NaN, -1 for invalid boxes.
//
// R6 counters: 45 us, VALUBusy 22.6%, Occupancy 6%, HBM 1.4% -> latency-bound
// (800 waves of 64 threads, serial logf chains + gather latency, no TLP).
// This round: BLK 256, flat (level,cell,class-part) work decomposition
// (CSPLIT=5 parts x 16 classes), select-add into 5 named f64 accumulators,
// single end-of-kernel reduction, invalid-box early exit.

#define NCLS   80
#define NLEV   5
#define MAXGT  100
#define TOTAL  13343
#define BLK    256
#define CSPLIT 5            // 80 classes / 5 parts = 16 classes = 4 float4s

__device__ __forceinline__ float fadd(float a, float b) { return __fadd_rn(a, b); }
__device__ __forceinline__ float fsub(float a, float b) { return __fsub_rn(a, b); }
__device__ __forceinline__ float fmul(float a, float b) { return __fmul_rn(a, b); }
__device__ __forceinline__ float fdv (float a, float b) { return __fdiv_rn(a, b); }

struct Rect { int x1, y1, w, cells; };

__device__ __forceinline__ Rect mkrect(float b0, float b1, float b2, float b3,
                                       float st, int fd) {
    // strict f32, reference op order (unchanged from R6)
    const float pb0 = fdv(b0, st), pb1 = fdv(b1, st);
    const float pb2 = fdv(b2, st), pb3 = fdv(b3, st);
    const float cx = fdv(fadd(pb0, pb2), 2.0f);
    const float cy = fdv(fadd(pb1, pb3), 2.0f);
    const float hw = fdv(fmul(fsub(pb2, pb0), 0.2f), 2.0f);
    const float hh = fdv(fmul(fsub(pb3, pb1), 0.2f), 2.0f);
    const int x1 = (int)fminf(fmaxf(floorf(fsub(cx, hw)), 0.0f), (float)(fd - 1));
    const int y1 = (int)fminf(fmaxf(floorf(fsub(cy, hh)), 0.0f), (float)(fd - 1));
    const int x2 = min(max((int)ceilf(fadd(cx, hw)), x1 + 1), fd);
    const int y2 = min(max((int)ceilf(fadd(cy, hh)), y1 + 1), fd);
    Rect r; r.x1 = x1; r.y1 = y1; r.w = x2 - x1; r.cells = (x2 - x1) * (y2 - y1);
    return r;
}

__device__ __forceinline__ double focal4(float4 v) {
    double s = 0.0;
    {
        const float cp = fminf(fmaxf(v.x, 1e-6f), 1.0f - 1e-6f);
        s += (double)(0.75f * cp * cp * (-logf(1.0f - cp)));
    }
    {
        const float cp = fminf(fmaxf(v.y, 1e-6f), 1.0f - 1e-6f);
        s += (double)(0.75f * cp * cp * (-logf(1.0f - cp)));
    }
    {
        const float cp = fminf(fmaxf(v.z, 1e-6f), 1.0f - 1e-6f);
        s += (double)(0.75f * cp * cp * (-logf(1.0f - cp)));
    }
    {
        const float cp = fminf(fmaxf(v.w, 1e-6f), 1.0f - 1e-6f);
        s += (double)(0.75f * cp * cp * (-logf(1.0f - cp)));
    }
    return s;
}

__device__ __forceinline__ double waveSumD(double v) {
    #pragma unroll
    for (int o = 32; o > 0; o >>= 1) v += __shfl_down(v, o, 64);
    return v;   // lane 0 holds the wave total
}

__global__ __launch_bounds__(BLK) void level_select_kernel(
    const float* __restrict__ cls_pred,
    const float* __restrict__ regr_pred,
    const float* __restrict__ gt_boxes,
    int* __restrict__ out)
{
    const int bn  = blockIdx.x;           // 0..799, one block per (b, gt)
    const int b   = bn / MAXGT;
    const int tid = threadIdx.x;

    const float* box = gt_boxes + (size_t)bn * 5;
    const float b0 = box[0], b1 = box[1], b2 = box[2], b3 = box[3];
    const float vsum = fabsf(b0) + fabsf(b1) + fabsf(b2) + fabsf(b3);
    if (!(vsum > 0.0f)) {                 // invalid box: losses never inspected
        if (tid == 0) out[bn] = -1;
        return;
    }
    const int label = (int)box[4];

    const float* clsB = cls_pred  + (size_t)b * TOTAL * NCLS;
    const float* rgB  = regr_pred + (size_t)b * TOTAL * 4;

    // per-level rects (block-uniform), named so no dynamic register indexing
    const Rect r0 = mkrect(b0, b1, b2, b3,   8.0f, 100);
    const Rect r1 = mkrect(b0, b1, b2, b3,  16.0f,  50);
    const Rect r2 = mkrect(b0, b1, b2, b3,  32.0f,  25);
    const Rect r3 = mkrect(b0, b1, b2, b3,  64.0f,  13);
    const Rect r4 = mkrect(b0, b1, b2, b3, 128.0f,   7);

    const int woff1 = r0.cells * CSPLIT;
    const int woff2 = woff1 + r1.cells * CSPLIT;
    const int woff3 = woff2 + r2.cells * CSPLIT;
    const int woff4 = woff3 + r3.cells * CSPLIT;
    const int total = woff4 + r4.cells * CSPLIT;

    double a0 = 0.0, a1 = 0.0, a2 = 0.0, a3 = 0.0, a4 = 0.0;

    for (int wk = tid; wk < total; wk += BLK) {
        const int l = (wk >= woff1) + (wk >= woff2) + (wk >= woff3) + (wk >= woff4);

        const int base = (l == 0) ? 0 : (l == 1) ? woff1 : (l == 2) ? woff2
                       : (l == 3) ? woff3 : woff4;
        const Rect  rr    = (l == 0) ? r0 : (l == 1) ? r1 : (l == 2) ? r2
                          : (l == 3) ? r3 : r4;
        const float st    = (l == 0) ? 8.0f : (l == 1) ? 16.0f : (l == 2) ? 32.0f
                          : (l == 3) ? 64.0f : 128.0f;
        const int   fw    = (l == 0) ? 100 : (l == 1) ? 50 : (l == 2) ? 25
                          : (l == 3) ? 13 : 7;
        const int   start = (l == 0) ? 0 : (l == 1) ? 10000 : (l == 2) ? 12500
                          : (l == 3) ? 13125 : 13294;

        const int rel  = wk - base;
        const int cell = rel / CSPLIT;            // magic-mul (const divisor)
        const int part = rel - cell * CSPLIT;
        const int cy   = cell / rr.w;             // runtime div, ~12 instr
        const int x    = rr.x1 + (cell - cy * rr.w);
        const int y    = rr.y1 + cy;
        const int p    = start + y * fw + x;

        // ---- 16-class focal slice ----
        const float4* crow = (const float4*)(clsB + (size_t)p * NCLS + part * 16);
        double val = focal4(crow[0]) + focal4(crow[1]) + focal4(crow[2]) + focal4(crow[3]);

        if (part == 0) {
            // ---- label term ----
            const float plab = fminf(fmaxf(clsB[(size_t)p * NCLS + label], 1e-6f),
                                     1.0f - 1e-6f);
            const float neg_lab = 0.75f * plab * plab * (-logf(1.0f - plab));
            const float one_m   = 1.0f - plab;
            const float pos_lab = 0.25f * one_m * one_m * (-logf(plab));
            val += (double)pos_lab - (double)neg_lab;

            // ---- IoU term (strict f32; NaN/inf propagate) ----
            const float4 rp = *(const float4*)(rgB + (size_t)p * 4);
            const float sx = fmul(fadd((float)x, 0.5f), st);
            const float sy = fmul(fadd((float)y, 0.5f), st);
            const float tl = fdv(fsub(sx, b0), 4.0f);
            const float tt = fdv(fsub(sy, b1), 4.0f);
            const float tr = fdv(fsub(b2, sx), 4.0f);
            const float tb = fdv(fsub(b3, sy), 4.0f);
            const float t_area = fmul(fadd(tl, tr), fadd(tt, tb));
            const float p_area = fmul(fadd(rp.x, rp.z), fadd(rp.y, rp.w));
            const float wi = fadd(fminf(rp.x, tl), fminf(rp.z, tr));
            const float hi = fadd(fminf(rp.y, tt), fminf(rp.w, tb));
            const float ai = fmul(wi, hi);
            const float num = fadd(ai, 1.0f);
            const float den = fadd(fsub(fadd(t_area, p_area), ai), 1.0f);
            val += (double)(-logf(fdv(num, den)));
        }

        a0 += (l == 0) ? val : 0.0;
        a1 += (l == 1) ? val : 0.0;
        a2 += (l == 2) ? val : 0.0;
        a3 += (l == 3) ? val : 0.0;
        a4 += (l == 4) ? val : 0.0;
    }

    // ---- block reduction: wave shuffles, then LDS across 4 waves ----
    a0 = waveSumD(a0); a1 = waveSumD(a1); a2 = waveSumD(a2);
    a3 = waveSumD(a3); a4 = waveSumD(a4);

    __shared__ double s_red[BLK / 64][NLEV];
    const int wave = tid >> 6, lane = tid & 63;
    if (lane == 0) {
        s_red[wave][0] = a0; s_red[wave][1] = a1; s_red[wave][2] = a2;
        s_red[wave][3] = a3; s_red[wave][4] = a4;
    }
    __syncthreads();

    if (tid == 0) {
        double lv[NLEV];
        const int cellsArr[NLEV] = {r0.cells, r1.cells, r2.cells, r3.cells, r4.cells};
        #pragma unroll
        for (int l = 0; l < NLEV; ++l) {
            double t = 0.0;
            #pragma unroll
            for (int w = 0; w < BLK / 64; ++w) t += s_red[w][l];
            lv[l] = t / (double)cellsArr[l];
        }
        // numpy argmin: FIRST NaN sticky; else strict-< (first index on ties)
        double best = INFINITY;
        int    idx  = 0;
        bool   accNan = false;
        #pragma unroll
        for (int l = 0; l < NLEV; ++l) {
            const double v = lv[l];
            if (!accNan && (isnan(v) || v < best)) {
                best = v; idx = l; accNan = isnan(v);
            }
        }
        out[bn] = idx;
    }
}

extern "C" void kernel_launch(void* const* d_in, const int* in_sizes, int n_in,
                              void* d_out, int out_size, void* d_ws, size_t ws_size,
                              hipStream_t stream) {
    (void)d_ws; (void)ws_size; (void)out_size;
    const float* cls_pred  = (const float*)d_in[0];
    const float* regr_pred = (const float*)d_in[1];
    const float* gt_boxes  = (const float*)d_in[3];
    for (int i = 0; i < n_in; ++i) {   // defensive mapping by element count
        if      (in_sizes[i] == 8 * TOTAL * NCLS) cls_pred  = (const float*)d_in[i];
        else if (in_sizes[i] == 8 * TOTAL * 4)    regr_pred = (const float*)d_in[i];
        else if (in_sizes[i] == 8 * MAXGT * 5)    gt_boxes  = (const float*)d_in[i];
    }
    int* out = (int*)d_out;

    level_select_kernel<<<8 * MAXGT, BLK, 0, stream>>>(cls_pred, regr_pred, gt_boxes, out);
}

// Round 8
// 86.528 us; speedup vs baseline: 1.3267x; 1.0316x over previous
//
#include <hip/hip_runtime.h>
#include <math.h>

// LevelSelect: FCOS-style FPN level assignment.  (R6/R7 passed: absmax 0)
// Semantics locked (rounds 0-6): masked-cells-only evaluation (XLA
// select-rewrite drops out-of-mask NaN/inf), strict non-contracted f32
// per-cell math in reference op order, f64 accumulation, numpy argmin with
// STICKY FIRST-NaN, -1 for invalid boxes.
//
// R7: kernel ~20us (dur_us 89.3; ~70us is harness reset overhead). Remaining
// kernel time = latency-serialized recompute of the 80-class focal sum per
// (box,cell) even though it's box-independent. This round splits into:
//   k1: s_neg[b][p] for ALL 8x13343 positions -> d_ws (quad-per-row, fully
//       coalesced stream of cls_pred; throughput-bound, not latency-bound)
//   k2: per-box wave: per masked cell, read s_neg (1 f64) + label prob +
//       regr float4, IoU term, select-add into 5 accumulators, wave reduce,
//       sticky-first-NaN argmin.
// Per-value f32 math identical to R6/R7; only f64 summation ORDER changes
// (<=1e-13 rel vs level gaps >= ~1e-3).

#define NCLS   80
#define NLEV   5
#define MAXGT  100
#define TOTAL  13343
#define NROWS  (8 * TOTAL)          // 106,744 positions

__device__ __forceinline__ float fadd(float a, float b) { return __fadd_rn(a, b); }
__device__ __forceinline__ float fsub(float a, float b) { return __fsub_rn(a, b); }
__device__ __forceinline__ float fmul(float a, float b) { return __fmul_rn(a, b); }
__device__ __forceinline__ float fdv (float a, float b) { return __fdiv_rn(a, b); }

__device__ __forceinline__ double focal4(float4 v) {
    double s = 0.0;
    {
        const float cp = fminf(fmaxf(v.x, 1e-6f), 1.0f - 1e-6f);
        s += (double)(0.75f * cp * cp * (-logf(1.0f - cp)));
    }
    {
        const float cp = fminf(fmaxf(v.y, 1e-6f), 1.0f - 1e-6f);
        s += (double)(0.75f * cp * cp * (-logf(1.0f - cp)));
    }
    {
        const float cp = fminf(fmaxf(v.z, 1e-6f), 1.0f - 1e-6f);
        s += (double)(0.75f * cp * cp * (-logf(1.0f - cp)));
    }
    {
        const float cp = fminf(fmaxf(v.w, 1e-6f), 1.0f - 1e-6f);
        s += (double)(0.75f * cp * cp * (-logf(1.0f - cp)));
    }
    return s;
}

// ---------------- k1: per-position 80-class focal sum ----------------------
// One quad (4 lanes) per row: lane sub reads float4s at 16B*sub + 64B*j
// -> each wave's loads cover 16 rows x 64B contiguous chunks (coalesced).
__global__ __launch_bounds__(256) void sneg_kernel(
    const float* __restrict__ cls_pred,
    double* __restrict__ sneg)
{
    const int t   = blockIdx.x * 256 + threadIdx.x;
    const int row = t >> 2;
    const int sub = t & 3;
    if (row >= NROWS) return;

    const float4* rp = (const float4*)(cls_pred + (size_t)row * NCLS) + sub;
    double s = 0.0;
    #pragma unroll
    for (int j = 0; j < 5; ++j)         // 5 float4s per lane = 20 classes
        s += focal4(rp[j * 4]);         // quad stride: 4 float4s = 64B

    s += __shfl_xor(s, 1, 64);          // quad reduction
    s += __shfl_xor(s, 2, 64);
    if (sub == 0) sneg[row] = s;
}

// ---------------- k2: per-box level losses + argmin ------------------------
struct Rect { int x1, y1, w, cells; };

__device__ __forceinline__ Rect mkrect(float b0, float b1, float b2, float b3,
                                       float st, int fd) {
    // strict f32, reference op order (unchanged from R6/R7)
    const float pb0 = fdv(b0, st), pb1 = fdv(b1, st);
    const float pb2 = fdv(b2, st), pb3 = fdv(b3, st);
    const float cx = fdv(fadd(pb0, pb2), 2.0f);
    const float cy = fdv(fadd(pb1, pb3), 2.0f);
    const float hw = fdv(fmul(fsub(pb2, pb0), 0.2f), 2.0f);
    const float hh = fdv(fmul(fsub(pb3, pb1), 0.2f), 2.0f);
    const int x1 = (int)fminf(fmaxf(floorf(fsub(cx, hw)), 0.0f), (float)(fd - 1));
    const int y1 = (int)fminf(fmaxf(floorf(fsub(cy, hh)), 0.0f), (float)(fd - 1));
    const int x2 = min(max((int)ceilf(fadd(cx, hw)), x1 + 1), fd);
    const int y2 = min(max((int)ceilf(fadd(cy, hh)), y1 + 1), fd);
    Rect r; r.x1 = x1; r.y1 = y1; r.w = x2 - x1; r.cells = (x2 - x1) * (y2 - y1);
    return r;
}

__device__ __forceinline__ double waveSumD(double v) {
    #pragma unroll
    for (int o = 32; o > 0; o >>= 1) v += __shfl_down(v, o, 64);
    return v;   // lane 0 holds the wave total
}

__global__ __launch_bounds__(64) void level_select_kernel(
    const float* __restrict__ cls_pred,
    const float* __restrict__ regr_pred,
    const float* __restrict__ gt_boxes,
    const double* __restrict__ sneg,
    int* __restrict__ out)
{
    const int bn  = blockIdx.x;           // 0..799, one wave per (b, gt)
    const int b   = bn / MAXGT;
    const int tid = threadIdx.x;

    const float* box = gt_boxes + (size_t)bn * 5;
    const float b0 = box[0], b1 = box[1], b2 = box[2], b3 = box[3];
    const float vsum = fabsf(b0) + fabsf(b1) + fabsf(b2) + fabsf(b3);
    if (!(vsum > 0.0f)) {                 // invalid box: losses never inspected
        if (tid == 0) out[bn] = -1;
        return;
    }
    const int label = (int)box[4];

    const float*  clsB  = cls_pred + (size_t)b * TOTAL * NCLS;
    const float*  rgB   = regr_pred + (size_t)b * TOTAL * 4;
    const double* snegB = sneg + (size_t)b * TOTAL;

    const Rect r0 = mkrect(b0, b1, b2, b3,   8.0f, 100);
    const Rect r1 = mkrect(b0, b1, b2, b3,  16.0f,  50);
    const Rect r2 = mkrect(b0, b1, b2, b3,  32.0f,  25);
    const Rect r3 = mkrect(b0, b1, b2, b3,  64.0f,  13);
    const Rect r4 = mkrect(b0, b1, b2, b3, 128.0f,   7);

    const int o1 = r0.cells;
    const int o2 = o1 + r1.cells;
    const int o3 = o2 + r2.cells;
    const int o4 = o3 + r3.cells;
    const int total = o4 + r4.cells;

    double a0 = 0.0, a1 = 0.0, a2 = 0.0, a3 = 0.0, a4 = 0.0;

    for (int c = tid; c < total; c += 64) {
        const int l = (c >= o1) + (c >= o2) + (c >= o3) + (c >= o4);

        const int base = (l == 0) ? 0 : (l == 1) ? o1 : (l == 2) ? o2
                       : (l == 3) ? o3 : o4;
        const Rect  rr    = (l == 0) ? r0 : (l == 1) ? r1 : (l == 2) ? r2
                          : (l == 3) ? r3 : r4;
        const float st    = (l == 0) ? 8.0f : (l == 1) ? 16.0f : (l == 2) ? 32.0f
                          : (l == 3) ? 64.0f : 128.0f;
        const int   fw    = (l == 0) ? 100 : (l == 1) ? 50 : (l == 2) ? 25
                          : (l == 3) ? 13 : 7;
        const int   start = (l == 0) ? 0 : (l == 1) ? 10000 : (l == 2) ? 12500
                          : (l == 3) ? 13125 : 13294;

        const int rel = c - base;
        const int cy  = rel / rr.w;
        const int x   = rr.x1 + (rel - cy * rr.w);
        const int y   = rr.y1 + cy;
        const int p   = start + y * fw + x;

        // ---- precomputed 80-class focal sum ----
        double val = snegB[p];

        // ---- label term ----
        const float plab = fminf(fmaxf(clsB[(size_t)p * NCLS + label], 1e-6f),
                                 1.0f - 1e-6f);
        const float neg_lab = 0.75f * plab * plab * (-logf(1.0f - plab));
        const float one_m   = 1.0f - plab;
        const float pos_lab = 0.25f * one_m * one_m * (-logf(plab));
        val += (double)pos_lab - (double)neg_lab;

        // ---- IoU term (strict f32; NaN/inf propagate into f64 sum) ----
        const float4 rp = *(const float4*)(rgB + (size_t)p * 4);
        const float sx = fmul(fadd((float)x, 0.5f), st);
        const float sy = fmul(fadd((float)y, 0.5f), st);
        const float tl = fdv(fsub(sx, b0), 4.0f);
        const float tt = fdv(fsub(sy, b1), 4.0f);
        const float tr = fdv(fsub(b2, sx), 4.0f);
        const float tb = fdv(fsub(b3, sy), 4.0f);
        const float t_area = fmul(fadd(tl, tr), fadd(tt, tb));
        const float p_area = fmul(fadd(rp.x, rp.z), fadd(rp.y, rp.w));
        const float wi = fadd(fminf(rp.x, tl), fminf(rp.z, tr));
        const float hi = fadd(fminf(rp.y, tt), fminf(rp.w, tb));
        const float ai = fmul(wi, hi);
        const float num = fadd(ai, 1.0f);
        const float den = fadd(fsub(fadd(t_area, p_area), ai), 1.0f);
        val += (double)(-logf(fdv(num, den)));

        a0 += (l == 0) ? val : 0.0;
        a1 += (l == 1) ? val : 0.0;
        a2 += (l == 2) ? val : 0.0;
        a3 += (l == 3) ? val : 0.0;
        a4 += (l == 4) ? val : 0.0;
    }

    a0 = waveSumD(a0); a1 = waveSumD(a1); a2 = waveSumD(a2);
    a3 = waveSumD(a3); a4 = waveSumD(a4);

    if (tid == 0) {
        double lv[NLEV];
        lv[0] = a0 / (double)r0.cells;
        lv[1] = a1 / (double)r1.cells;
        lv[2] = a2 / (double)r2.cells;
        lv[3] = a3 / (double)r3.cells;
        lv[4] = a4 / (double)r4.cells;
        // numpy argmin: FIRST NaN sticky; else strict-< (first index on ties)
        double best = INFINITY;
        int    idx  = 0;
        bool   accNan = false;
        #pragma unroll
        for (int l = 0; l < NLEV; ++l) {
            const double v = lv[l];
            if (!accNan && (isnan(v) || v < best)) {
                best = v; idx = l; accNan = isnan(v);
            }
        }
        out[bn] = idx;
    }
}

extern "C" void kernel_launch(void* const* d_in, const int* in_sizes, int n_in,
                              void* d_out, int out_size, void* d_ws, size_t ws_size,
                              hipStream_t stream) {
    (void)out_size;
    const float* cls_pred  = (const float*)d_in[0];
    const float* regr_pred = (const float*)d_in[1];
    const float* gt_boxes  = (const float*)d_in[3];
    for (int i = 0; i < n_in; ++i) {   // defensive mapping by element count
        if      (in_sizes[i] == 8 * TOTAL * NCLS) cls_pred  = (const float*)d_in[i];
        else if (in_sizes[i] == 8 * TOTAL * 4)    regr_pred = (const float*)d_in[i];
        else if (in_sizes[i] == 8 * MAXGT * 5)    gt_boxes  = (const float*)d_in[i];
    }
    int* out = (int*)d_out;
    double* sneg = (double*)d_ws;       // 106,744 * 8 B = 854 KB (ws is 256 MB)
    (void)ws_size;

    // k1: 4 threads per row, 256/block
    const int k1_threads = NROWS * 4;
    const int k1_blocks  = (k1_threads + 255) / 256;
    sneg_kernel<<<k1_blocks, 256, 0, stream>>>(cls_pred, sneg);

    // k2: one 64-thread wave per (b, gt)
    level_select_kernel<<<8 * MAXGT, 64, 0, stream>>>(
        cls_pred, regr_pred, gt_boxes, sneg, out);
}